// Round 1
// baseline (458.956 us; speedup 1.0000x reference)
//
#include <hip/hip_runtime.h>

// DistMult edge score: out[e] = sum_d node_emb[src[e]][d] * rel_emb[e][d] * node_emb[dst[e]][d]
// N_NODES = 100000, N_EDGES = 600000, DIM = 128, all fp32, indices int32.
//
// Strategy: memory-bound gather + stream. Half-wave (32 lanes) per edge,
// float4 per lane (32 * 4 = 128 floats = one row). Shuffle-reduce within the
// 32-lane group. Block 256 = 8 edges/block.

#define DIM 128
#define EDGES_PER_BLOCK 8

__global__ __launch_bounds__(256) void distmult_score_kernel(
    const float* __restrict__ node_emb,
    const float* __restrict__ rel_emb,
    const int*   __restrict__ src,
    const int*   __restrict__ dst,
    float*       __restrict__ out,
    int E)
{
    const int tid    = threadIdx.x;       // 0..255
    const int half   = tid >> 5;          // 0..7 : which edge within block
    const int lane32 = tid & 31;          // 0..31 : float4 slot within row

    const int e = blockIdx.x * EDGES_PER_BLOCK + half;
    if (e >= E) return;                   // uniform across each 32-lane group

    const int s = src[e];
    const int d = dst[e];

    const float4* __restrict__ hp = (const float4*)(node_emb + (long long)s * DIM);
    const float4* __restrict__ tp = (const float4*)(node_emb + (long long)d * DIM);
    const float4* __restrict__ rp = (const float4*)(rel_emb  + (long long)e * DIM);

    const float4 h = hp[lane32];
    const float4 r = rp[lane32];
    const float4 t = tp[lane32];

    float v = h.x * r.x * t.x
            + h.y * r.y * t.y
            + h.z * r.z * t.z
            + h.w * r.w * t.w;

    // Reduce across the 32-lane half-wave (width=32 keeps groups separate).
    #pragma unroll
    for (int off = 16; off > 0; off >>= 1)
        v += __shfl_xor(v, off, 32);

    if (lane32 == 0) out[e] = v;
}

extern "C" void kernel_launch(void* const* d_in, const int* in_sizes, int n_in,
                              void* d_out, int out_size, void* d_ws, size_t ws_size,
                              hipStream_t stream) {
    const float* node_emb = (const float*)d_in[0];
    const float* rel_emb  = (const float*)d_in[1];
    const int*   src      = (const int*)d_in[2];
    const int*   dst      = (const int*)d_in[3];
    float*       out      = (float*)d_out;

    const int E = in_sizes[2];  // 600000 edges

    const int grid = (E + EDGES_PER_BLOCK - 1) / EDGES_PER_BLOCK;
    distmult_score_kernel<<<grid, 256, 0, stream>>>(node_emb, rel_emb, src, dst, out, E);
}